// Round 1
// baseline (418.740 us; speedup 1.0000x reference)
//
#include <hip/hip_runtime.h>
#include <hip/hip_bf16.h>

// Problem constants
#define B_    8
#define C_    32
#define O_    64
#define GIN   33
#define GOUT  15
#define GF    7
#define XDIM  64
#define KK    5
#define XOUT  60
#define CCH   224      // C_*GF  (GEMM K per tap)
#define TAPS  25
#define CCHUNK 32      // channels staged per chunk (one MFMA K=32 step)
#define RPAD  40       // LDS channel-slot stride (32 + 8 pad -> conflict-friendly, 16B aligned)
#define ROWS  8        // staged input rows per tile (4 out rows + 4 halo)
#define TILE_ROWS 4
#define TILE_POS  240  // TILE_ROWS*60
#define NFRAGS 15      // TILE_POS/16

typedef __attribute__((ext_vector_type(8))) __bf16 bf16x8;
typedef __attribute__((ext_vector_type(8))) unsigned short u16x8;
typedef __attribute__((ext_vector_type(4))) float f32x4;

__device__ __forceinline__ f32x4 mfma16(u16x8 a, u16x8 b, f32x4 c) {
  return __builtin_amdgcn_mfma_f32_16x16x32_bf16(
      __builtin_bit_cast(bf16x8, a), __builtin_bit_cast(bf16x8, b), c, 0, 0, 0);
}

// Pre-transform weights: weight[o][c][f][kh][kw] f32 -> Wt[tap][o][cc] bf16, cc=c*7+f, tap=kh*5+kw
__global__ void wt_kernel(const float* __restrict__ w, unsigned short* __restrict__ wt) {
  int i = blockIdx.x * 256 + threadIdx.x;
  if (i >= TAPS * O_ * CCH) return;
  int cc  = i % CCH;
  int o   = (i / CCH) % O_;
  int tap = i / (CCH * O_);
  int c = cc / GF, f = cc % GF;
  float v = w[(size_t)o * (C_ * GF * KK * KK) + c * (GF * KK * KK) + f * (KK * KK) + tap];
  __bf16 hb = (__bf16)v;
  wt[i] = __builtin_bit_cast(unsigned short, hb);
}

__global__ void __launch_bounds__(256, 3)
conv_kernel(const float* __restrict__ x, const unsigned short* __restrict__ wt,
            const float* __restrict__ bias, const int* __restrict__ idx,
            float* __restrict__ out) {
  __shared__ __align__(16) unsigned short Xs[ROWS * 64 * RPAD];  // 40 KB
  __shared__ int   sImg[CCH];
  __shared__ float sBias[O_];

  const int bid  = blockIdx.x;
  const int tile = bid % 15;
  const int g    = (bid / 15) % GOUT;
  const int b    = bid / (15 * GOUT);

  const int tid  = threadIdx.x;
  const int lane = tid & 63;
  const int wv   = tid >> 6;    // wave id 0..3
  const int lo   = lane & 15;
  const int lk   = lane >> 4;   // 0..3

  if (tid < CCH) {
    int c = tid / GF, f = tid % GF;
    int gin = idx[g * GF + f];
    sImg[tid] = ((b * C_ + c) * GIN + gin) * (XDIM * XDIM);
  }
  if (tid < O_) sBias[tid] = bias[tid];

  // Per-lane B-fragment base offsets for this wave's n-frags (flattened position space).
  int bbase[4];
  int nvalid = 0;
#pragma unroll
  for (int i = 0; i < 4; ++i) {
    int nf = wv * 4 + i;
    if (nf < NFRAGS) {
      int p  = nf * 16 + lo;        // 0..239
      int ph = p / 60, pw = p - ph * 60;
      bbase[i] = (ph * 64 + pw) * RPAD + 8 * lk;
      nvalid = i + 1;
    }
  }

  f32x4 acc[4][4];
#pragma unroll
  for (int m = 0; m < 4; ++m)
#pragma unroll
    for (int i = 0; i < 4; ++i) acc[m][i] = f32x4{0.f, 0.f, 0.f, 0.f};

  const int r0  = tile * TILE_ROWS;  // first staged input row (global)
  const int col = tid & 63;
  const int rh  = tid >> 6;          // 0..3 -> rows 2*rh, 2*rh+1
  const int wlane_base = lo * CCH + 8 * lk;  // A-frag per-lane offset

  for (int c0 = 0; c0 < CCH; c0 += CCHUNK) {
    __syncthreads();  // Xs free to overwrite (also covers sImg/sBias init on first pass)
    // ---- stage 32 channels x 8 rows x 64 cols, f32 -> bf16, channel-innermost ----
#pragma unroll
    for (int jp = 0; jp < 16; ++jp) {
      int ib0 = sImg[c0 + 2 * jp];
      int ib1 = sImg[c0 + 2 * jp + 1];
#pragma unroll
      for (int rr = 0; rr < 2; ++rr) {
        int r  = rh * 2 + rr;
        int ga = (r0 + r) * XDIM + col;
        float v0 = x[ib0 + ga];
        float v1 = x[ib1 + ga];
        unsigned int u0 = __builtin_bit_cast(unsigned short, (__bf16)v0);
        unsigned int u1 = __builtin_bit_cast(unsigned short, (__bf16)v1);
        *reinterpret_cast<unsigned int*>(&Xs[(r * 64 + col) * RPAD + 2 * jp]) =
            u0 | (u1 << 16);
      }
    }
    __syncthreads();

    // ---- 25 taps x (4 A-frags, <=4 B-frags, 16 MFMA) ----
    for (int tap = 0; tap < TAPS; ++tap) {
      int kh = tap / 5, kw = tap - 5 * (tap / 5);
      int toff = (kh * 64 + kw) * RPAD;
      u16x8 a[4], bf[4];
#pragma unroll
      for (int m = 0; m < 4; ++m)
        a[m] = *reinterpret_cast<const u16x8*>(
            wt + tap * (O_ * CCH) + m * 16 * CCH + wlane_base + c0);
#pragma unroll
      for (int i = 0; i < 4; ++i)
        if (i < nvalid)
          bf[i] = *reinterpret_cast<const u16x8*>(&Xs[bbase[i] + toff]);
#pragma unroll
      for (int i = 0; i < 4; ++i)
        if (i < nvalid)
#pragma unroll
          for (int m = 0; m < 4; ++m)
            acc[m][i] = mfma16(a[m], bf[i], acc[m][i]);
    }
  }

  // ---- epilogue: acc + bias -> out[b][o][g][ph][pw] (f32) ----
  const size_t obase = ((size_t)b * O_ * GOUT + g) * 3600 + (size_t)tile * TILE_POS;
#pragma unroll
  for (int m = 0; m < 4; ++m) {
#pragma unroll
    for (int i = 0; i < 4; ++i) {
      if (i < nvalid) {
        int nf = wv * 4 + i;
        int p  = nf * 16 + lo;
#pragma unroll
        for (int v = 0; v < 4; ++v) {
          int o = m * 16 + 4 * lk + v;
          out[obase + (size_t)o * (GOUT * 3600) + p] = acc[m][i][v] + sBias[o];
        }
      }
    }
  }
}

extern "C" void kernel_launch(void* const* d_in, const int* in_sizes, int n_in,
                              void* d_out, int out_size, void* d_ws, size_t ws_size,
                              hipStream_t stream) {
  const float* x      = (const float*)d_in[0];
  const float* weight = (const float*)d_in[1];
  const float* bias   = (const float*)d_in[2];
  const int*   idx    = (const int*)d_in[3];
  float* out = (float*)d_out;
  unsigned short* wt = (unsigned short*)d_ws;  // 25*64*224*2 = 716800 B

  wt_kernel<<<(TAPS * O_ * CCH + 255) / 256, 256, 0, stream>>>(weight, wt);
  conv_kernel<<<B_ * GOUT * 15, 256, 0, stream>>>(x, wt, bias, idx, out);
}